// Round 5
// baseline (411.639 us; speedup 1.0000x reference)
//
#include <hip/hip_runtime.h>

typedef __bf16  bf16x8 __attribute__((ext_vector_type(8)));
typedef float   f32x4  __attribute__((ext_vector_type(4)));
typedef unsigned short u16x8 __attribute__((ext_vector_type(8)));

__device__ __forceinline__ unsigned short f2bf(float f) {
    union { float f; unsigned int u; } v; v.f = f;
    unsigned int u = v.u;
    unsigned int r = (u + 0x7fffu + ((u >> 16) & 1u)) >> 16;
    return (unsigned short)r;
}

// pack two floats -> two bf16 in one dword
__device__ __forceinline__ unsigned int pkbf(float lo, float hi) {
    union { float f; unsigned int u; } a, b; a.f = lo; b.f = hi;
    return __builtin_amdgcn_perm(b.u + 0x8000u, a.u + 0x8000u, 0x07060302u);
}

// async global->LDS, 16B per lane. LDS dest = wave-uniform base + lane*16.
__device__ __forceinline__ void gld_lds16(const void* g, void* l) {
    auto gp = (const __attribute__((address_space(1))) unsigned int*)g;
    auto lp = (__attribute__((address_space(3))) unsigned int*)(unsigned int)(unsigned long long)l;
    __builtin_amdgcn_global_load_lds(gp, lp, 16, 0, 0);
}

// 4 weight matrices (1M fp32 each) -> bf16, one launch
__global__ void cast4_kernel(const float* __restrict__ a, const float* __restrict__ b,
                             const float* __restrict__ c, const float* __restrict__ d,
                             unsigned short* __restrict__ dst) {
    int sel = blockIdx.x >> 10;
    int off4 = (blockIdx.x & 1023) * 256 + threadIdx.x;
    const float* src = sel == 0 ? a : sel == 1 ? b : sel == 2 ? c : d;
    float4 f = ((const float4*)src)[off4];
    uint2 pk; pk.x = pkbf(f.x, f.y); pk.y = pkbf(f.z, f.w);
    ((uint2*)(dst + (size_t)sel * 1048576))[off4] = pk;
}

// read a bf16x8 A-fragment from the XOR-swizzled fp32 LDS tile
__device__ __forceinline__ bf16x8 read_af32(const float* As, int R, int q) {
    const int m = R & 7;
    const float4 v0 = *(const float4*)&As[R * 32 + (((2 * q)     ^ m) * 4)];
    const float4 v1 = *(const float4*)&As[R * 32 + (((2 * q + 1) ^ m) * 4)];
    union { unsigned int u[4]; bf16x8 v; } r;
    r.u[0] = pkbf(v0.x, v0.y); r.u[1] = pkbf(v0.z, v0.w);
    r.u[2] = pkbf(v1.x, v1.y); r.u[3] = pkbf(v1.z, v1.w);
    return r.v;
}

// Fused QKV projection: C_z = A_z (8192x1024 fp32) * W_z(1024x1024 bf16)^T.
// A staged as fp32 via global_load_lds with XOR-swizzled 16B chunks
// (chunk_glob = chunk_lds ^ (row&7)) -> conflict-free frag reads, no pre-cast.
// grid (64, 8, 3): z=0 -> V^T scatter [N,H,D,S]; z=1 -> K [N,H,S,D]; z=2 -> Q scaled.
// 1536 blocks, LDS 48KB -> 3 blocks/CU, two clean rounds.
__global__ __launch_bounds__(256, 3)
void qkv_gemm(const float* __restrict__ Vg, const float* __restrict__ Kg,
              const float* __restrict__ Qg, const unsigned short* __restrict__ W,
              unsigned short* __restrict__ Vtb, unsigned short* __restrict__ Kb,
              unsigned short* __restrict__ Qb, float qscale)
{
    constexpr int K = 1024;
    __shared__ float          Asf[2][4096];   // 128 x 32 fp32, swizzled
    __shared__ unsigned short Bs [2][4096];   // 128 x 32 bf16

    const int z = blockIdx.z;
    const float* A = z == 0 ? Vg : (z == 1 ? Kg : Qg);
    const unsigned short* Bt = W + (size_t)z * 1048576;
    const float a_scale = z == 2 ? qscale : 1.f;

    const int t    = threadIdx.x;
    const int lane = t & 63;
    const int w    = t >> 6;
    const int q    = lane >> 4;
    const int ln   = lane & 15;
    const int wr   = w >> 1, wc = w & 1;
    const int m0   = blockIdx.x * 128;
    const int n0   = blockIdx.y * 128;
    const int srow = lane >> 2, scol = (lane & 3) * 8;       // B staging
    const int arow = lane >> 3;                               // A staging: 8 rows/step
    const int achk = (lane & 7) ^ (arow & 7);                 // swizzled global chunk

    f32x4 acc[4][4];
    const f32x4 zz = {0.f, 0.f, 0.f, 0.f};
#pragma unroll
    for (int i = 0; i < 4; ++i)
#pragma unroll
        for (int j = 0; j < 4; ++j) acc[i][j] = zz;

    auto stage = [&](int k0, int p) {
#pragma unroll
        for (int s = 0; s < 4; ++s)
            gld_lds16(A + (size_t)(m0 + w * 32 + s * 8 + arow) * K + k0 + achk * 4,
                      &Asf[p][w * 1024 + s * 256 + lane * 4]);
#pragma unroll
        for (int c = 0; c < 2; ++c) {
            int u = w * 2 + c;
            gld_lds16(Bt + (size_t)(n0 + u * 16 + srow) * K + k0 + scol, &Bs[p][u * 512]);
        }
    };

    stage(0, 0);
    for (int j = 0; j < 32; ++j) {
        __syncthreads();
        if (j < 31) stage((j + 1) * 32, (j + 1) & 1);
        const int p = j & 1;
        bf16x8 af[4], bfr[4];
#pragma unroll
        for (int i = 0; i < 4; ++i)
            af[i] = read_af32(Asf[p], wr * 64 + i * 16 + ln, q);
#pragma unroll
        for (int jj = 0; jj < 4; ++jj)
            bfr[jj] = *(const bf16x8*)&Bs[p][(wc * 64 + jj * 16 + ln) * 32 + q * 8];
#pragma unroll
        for (int i = 0; i < 4; ++i)
#pragma unroll
            for (int jj = 0; jj < 4; ++jj)
                acc[i][jj] = __builtin_amdgcn_mfma_f32_16x16x32_bf16(af[i], bfr[jj], acc[i][jj], 0, 0, 0);
    }

    // epilogue: C/D layout row=(lane>>4)*4+r, col=lane&15
#pragma unroll
    for (int i = 0; i < 4; ++i) {
#pragma unroll
        for (int j = 0; j < 4; ++j) {
            f32x4 c = acc[i][j];
            int mb = m0 + wr * 64 + i * 16 + q * 4;
            int nn = n0 + wc * 64 + j * 16 + ln;
            int b = mb >> 11, s = mb & 2047, h = nn >> 6, d = nn & 63;
            if (z == 0) {                                  // V^T [N,H,D,S], 8B packed
                uint2 pk;
                pk.x = pkbf(c[0], c[1]);
                pk.y = pkbf(c[2], c[3]);
                size_t idx = (((size_t)(b * 16 + h) * 64) + d) * 2048 + s;
                *(uint2*)&Vtb[idx] = pk;
            } else {                                       // K/Q [N,H,S,D]
                unsigned short* dst = z == 1 ? Kb : Qb;
#pragma unroll
                for (int r = 0; r < 4; ++r) {
                    size_t idx = (((size_t)(b * 16 + h) * 2048) + (s + r)) * 64 + d;
                    dst[idx] = f2bf(c[r] * a_scale);
                }
            }
        }
    }
}

// Output projection with split-K=2: out must be pre-zeroed; both halves atomicAdd,
// z==0 also adds bias. A bf16 (Ob), 128x128 tiles, grid (64, 8, 2) = 4 blocks/CU.
__global__ __launch_bounds__(256, 4)
void out_gemm(const unsigned short* __restrict__ A, const unsigned short* __restrict__ Bt,
              float* __restrict__ out, const float* __restrict__ bias)
{
    constexpr int K = 1024;
    __shared__ unsigned short As[2][4096];
    __shared__ unsigned short Bs[2][4096];

    const int t    = threadIdx.x;
    const int lane = t & 63;
    const int w    = t >> 6;
    const int q    = lane >> 4;
    const int ln   = lane & 15;
    const int wr   = w >> 1, wc = w & 1;
    const int m0   = blockIdx.x * 128;
    const int n0   = blockIdx.y * 128;
    const int kb   = blockIdx.z * 512;
    const int srow = lane >> 2, scol = (lane & 3) * 8;

    f32x4 acc[4][4];
    const f32x4 zz = {0.f, 0.f, 0.f, 0.f};
#pragma unroll
    for (int i = 0; i < 4; ++i)
#pragma unroll
        for (int j = 0; j < 4; ++j) acc[i][j] = zz;

    auto stage = [&](int k0, int p) {
#pragma unroll
        for (int c = 0; c < 2; ++c) {
            int u = w * 2 + c;
            gld_lds16(A  + (size_t)(m0 + u * 16 + srow) * K + k0 + scol, &As[p][u * 512]);
            gld_lds16(Bt + (size_t)(n0 + u * 16 + srow) * K + k0 + scol, &Bs[p][u * 512]);
        }
    };

    stage(kb, 0);
    for (int j = 0; j < 16; ++j) {
        __syncthreads();
        if (j < 15) stage(kb + (j + 1) * 32, (j + 1) & 1);
        const int p = j & 1;
        bf16x8 af[4], bfr[4];
#pragma unroll
        for (int i = 0; i < 4; ++i)
            af[i] = *(const bf16x8*)&As[p][(wr * 64 + i * 16 + ln) * 32 + q * 8];
#pragma unroll
        for (int jj = 0; jj < 4; ++jj)
            bfr[jj] = *(const bf16x8*)&Bs[p][(wc * 64 + jj * 16 + ln) * 32 + q * 8];
#pragma unroll
        for (int i = 0; i < 4; ++i)
#pragma unroll
            for (int jj = 0; jj < 4; ++jj)
                acc[i][jj] = __builtin_amdgcn_mfma_f32_16x16x32_bf16(af[i], bfr[jj], acc[i][jj], 0, 0, 0);
    }

    const bool addb = (blockIdx.z == 0);
#pragma unroll
    for (int i = 0; i < 4; ++i) {
#pragma unroll
        for (int j = 0; j < 4; ++j) {
            f32x4 c = acc[i][j];
            int mb = m0 + wr * 64 + i * 16 + q * 4;
            int nn = n0 + wc * 64 + j * 16 + ln;
            float bv = addb ? bias[nn] : 0.f;
#pragma unroll
            for (int r = 0; r < 4; ++r)
                atomicAdd(&out[(size_t)(mb + r) * 1024 + nn], c[r] + bv);
        }
    }
}

// Flash attention, transposed-S, no online max. 256-row Q tiles, ti=4 per wave.
// S^T = K Q^T ; O^T = V^T P^T. Q pre-scaled by log2e/sqrt(E).
// Q,K [head][s][d]; Vt [head][d][s]. O bf16 [N,S,E].
// grid (64 heads, 8 qt) = 512 = exactly 2 blocks/CU (LDS 69632), zero tail.
__global__ __launch_bounds__(256, 2)
void attn_kernel(const unsigned short* __restrict__ Q, const unsigned short* __restrict__ Kg,
                 const unsigned short* __restrict__ Vt, unsigned short* __restrict__ Og)
{
    __shared__ unsigned short Ks[2][4096];    // 64 keys x 64 d (2 kc panels of 64x32)
    __shared__ unsigned short Vs[2][4096];    // 64 d x 64 keys (2 kc panels of 64x32)
    __shared__ unsigned short Ps[256 * 72];   // 256 qrows x 64 keys, stride 72

    const int t    = threadIdx.x;
    const int lane = t & 63;
    const int w    = t >> 6;
    const int q    = lane >> 4;
    const int ln   = lane & 15;
    const int head = blockIdx.x;
    const int qt   = blockIdx.y;

    const unsigned short* Qh  = Q  + (size_t)head * 2048 * 64;
    const unsigned short* Kh  = Kg + (size_t)head * 2048 * 64;
    const unsigned short* Vth = Vt + (size_t)head * 64 * 2048;

    const int srow = lane >> 2;
    const int scol = (lane & 3) * 8;

    // Q as B-fragments (qrow in lanes, k = d): wave owns 64 qrows
    bf16x8 qf[4][2];
    const int rowb = qt * 256 + w * 64;
#pragma unroll
    for (int ti = 0; ti < 4; ++ti)
#pragma unroll
        for (int kc = 0; kc < 2; ++kc)
            qf[ti][kc] = *(const bf16x8*)&Qh[(size_t)(rowb + ti * 16 + ln) * 64 + kc * 32 + q * 8];

    const f32x4 zz = {0.f, 0.f, 0.f, 0.f};
    f32x4 oa[4][4];
#pragma unroll
    for (int ti = 0; ti < 4; ++ti)
#pragma unroll
        for (int dt = 0; dt < 4; ++dt) oa[ti][dt] = zz;
    float l_s[4] = {0.f, 0.f, 0.f, 0.f};

    // stage 64-key tile j into buffer p: wave w covers rows w*16..+15 of both panels
    auto stage = [&](int j, int p) {
#pragma unroll
        for (int kc = 0; kc < 2; ++kc) {
            gld_lds16(Kh + (size_t)(j * 64 + w * 16 + srow) * 64 + kc * 32 + scol,
                      &Ks[p][kc * 2048 + w * 512]);
            gld_lds16(Vth + (size_t)(w * 16 + srow) * 2048 + j * 64 + kc * 32 + scol,
                      &Vs[p][kc * 2048 + w * 512]);
        }
    };

    stage(0, 0);
    for (int j = 0; j < 32; ++j) {
        __syncthreads();                       // drains gld(j); reads of other buf done
        if (j < 31) stage(j + 1, (j + 1) & 1);
        const int p = j & 1;

        // ---- streamed S^T = K Q^T + softmax, per 16-key group ----
        float rs[4] = {0.f, 0.f, 0.f, 0.f};
#pragma unroll
        for (int kt = 0; kt < 4; ++kt) {
            bf16x8 ka0 = *(const bf16x8*)&Ks[p][(kt * 16 + ln) * 32 + q * 8];
            bf16x8 ka1 = *(const bf16x8*)&Ks[p][2048 + (kt * 16 + ln) * 32 + q * 8];
            f32x4 sa[4];
#pragma unroll
            for (int ti = 0; ti < 4; ++ti) {
                sa[ti] = __builtin_amdgcn_mfma_f32_16x16x32_bf16(ka0, qf[ti][0], zz, 0, 0, 0);
                sa[ti] = __builtin_amdgcn_mfma_f32_16x16x32_bf16(ka1, qf[ti][1], sa[ti], 0, 0, 0);
            }
#pragma unroll
            for (int ti = 0; ti < 4; ++ti) {
                float p0 = exp2f(sa[ti][0]);
                float p1 = exp2f(sa[ti][1]);
                float p2 = exp2f(sa[ti][2]);
                float p3 = exp2f(sa[ti][3]);
                rs[ti] += (p0 + p1) + (p2 + p3);
                uint2 pk;
                pk.x = pkbf(p0, p1);
                pk.y = pkbf(p2, p3);
                *(uint2*)&Ps[(w * 64 + ti * 16 + ln) * 72 + kt * 16 + q * 4] = pk;
            }
        }
#pragma unroll
        for (int ti = 0; ti < 4; ++ti) {
            float r = rs[ti];
            r += __shfl_xor(r, 16);
            r += __shfl_xor(r, 32);
            l_s[ti] += r;
        }

        // ---- O^T += V^T P^T (wave-private P rows: no barrier) ----
#pragma unroll
        for (int kc = 0; kc < 2; ++kc) {
            bf16x8 va[4], pb[4];
#pragma unroll
            for (int dt = 0; dt < 4; ++dt)
                va[dt] = *(const bf16x8*)&Vs[p][kc * 2048 + (dt * 16 + ln) * 32 + q * 8];
#pragma unroll
            for (int ti = 0; ti < 4; ++ti)
                pb[ti] = *(const bf16x8*)&Ps[(w * 64 + ti * 16 + ln) * 72 + kc * 32 + q * 8];
#pragma unroll
            for (int ti = 0; ti < 4; ++ti)
#pragma unroll
                for (int dt = 0; dt < 4; ++dt)
                    oa[ti][dt] = __builtin_amdgcn_mfma_f32_16x16x32_bf16(va[dt], pb[ti], oa[ti][dt], 0, 0, 0);
        }
    }

    // ---- finalize: O = (O^T)^T / l, packed 8B stores ----
    const int n = head >> 4;
    const int hbase = (head & 15) * 64;
#pragma unroll
    for (int ti = 0; ti < 4; ++ti) {
        float inv = 1.f / l_s[ti];
        int sr = qt * 256 + w * 64 + ti * 16 + ln;
        size_t base = ((size_t)n * 2048 + sr) * 1024 + hbase;
#pragma unroll
        for (int dt = 0; dt < 4; ++dt) {
            uint2 pk;
            pk.x = pkbf(oa[ti][dt][0] * inv, oa[ti][dt][1] * inv);
            pk.y = pkbf(oa[ti][dt][2] * inv, oa[ti][dt][3] * inv);
            *(uint2*)&Og[base + dt * 16 + q * 4] = pk;
        }
    }
}

extern "C" void kernel_launch(void* const* d_in, const int* in_sizes, int n_in,
                              void* d_out, int out_size, void* d_ws, size_t ws_size,
                              hipStream_t stream)
{
    (void)in_sizes; (void)n_in; (void)out_size; (void)ws_size;
    const float* values  = (const float*)d_in[0];
    const float* keys    = (const float*)d_in[1];
    const float* queries = (const float*)d_in[2];
    const float* Wv = (const float*)d_in[3];
    const float* Wk = (const float*)d_in[4];
    const float* Wq = (const float*)d_in[5];
    const float* Wo = (const float*)d_in[6];
    const float* bo = (const float*)d_in[7];
    float* out = (float*)d_out;

    unsigned short* ws   = (unsigned short*)d_ws;
    unsigned short* Wb   = ws;                    // weights: Wv,Wk,Wq,Wo 1M each
    unsigned short* Wo_b = ws + 3145728;
    unsigned short* Qb   = ws + 4194304;          // 8M elems each
    unsigned short* Kb   = Qb + 8388608;
    unsigned short* Vtb  = Kb + 8388608;
    unsigned short* Ob   = Vtb + 8388608;         // total 36M shorts = 72 MB

    const float qscale = 1.4426950408889634f / 32.f;   // log2(e)/sqrt(E)

    cast4_kernel<<<4096, 256, 0, stream>>>(Wv, Wk, Wq, Wo, Wb);
    hipMemsetAsync(out, 0, (size_t)8192 * 1024 * 4, stream);

    qkv_gemm<<<dim3(64, 8, 3), 256, 0, stream>>>(values, keys, queries, Wb,
                                                 Vtb, Kb, Qb, qscale);
    attn_kernel<<<dim3(64, 8), 256, 0, stream>>>(Qb, Kb, Vtb, Ob);
    out_gemm<<<dim3(64, 8, 2), 256, 0, stream>>>(Ob, Wo_b, out, bo);
}